// Round 5
// baseline (26203.738 us; speedup 1.0000x reference)
//
#include <hip/hip_runtime.h>
#include <cstdint>

// TinyVanillaRNN: T=16384 sequential steps h = tanh(U[:,x_t] + W h + bh);
// logits[t] = V h_t + by. out = [logits (T*O) | h_T (H)], fp32.
//
// R5: single-XCD election + dual-channel handoff (hang-proof).
// 256 blocks (1/CU, co-resident). Each registers its XCC_ID on a per-XCD
// counter; the 32nd registrant on any XCD elects it by CAS (pigeonhole over
// 256 blocks -> always resolves). Ranks 0..31 on the chosen XCD are workers.
// Handoff, tagged u64 (step<<32 | f32 bits), parity double buffer:
//   FAST: volatile u64 store (write-through L1 -> value lands IN local L2)
//         + volatile u64 poll (sc0: L1-bypass, local-L2 read). Same-XCD
//         rendezvous at ~L2-hit latency.
//   SLOW: mirrored __hip_atomic_store(RELAXED, AGENT) (the R2/R3-proven
//         channel), checked every 8th poll -> if the fast channel is dead
//         for ANY reason we degrade to ~R3 speed, never hang.
// Compute body identical to R3: thread = 4 W-rows x 16 k (64 W floats in
// VGPRs), 7-shuffle select+butterfly reduce, V-frag logits computed from the
// matvec h registers in the post-publish shadow.

constexpr int T_STEPS = 16384;
constexpr int D_DIM   = 512;
constexpr int H_DIM   = 1024;
constexpr int O_DIM   = 512;
constexpr int NGRID   = 256;
constexpr int NWORK   = 32;
constexpr int NTHR    = 512;

__device__ __forceinline__ float fast_tanh(float x) {
    float e = __expf(2.f * x);
    return 1.f - 2.f / (e + 1.f);
}
__device__ __forceinline__ float hsum4(const float4& v) {
    return (v.x + v.y) + (v.z + v.w);
}

// Dual-channel acquire: 7 fast (volatile/sc0, local L2) : 1 slow (agent).
__device__ __forceinline__ float2 acquire_pair(
    const volatile unsigned long long* fp,
    const unsigned long long* sp, unsigned want)
{
    unsigned long long a, b;
    int k = 0;
    for (;;) {
        if ((k++ & 7) != 7) {
            a = fp[0];
            b = fp[1];
        } else {
            a = __hip_atomic_load(sp + 0, __ATOMIC_RELAXED, __HIP_MEMORY_SCOPE_AGENT);
            b = __hip_atomic_load(sp + 1, __ATOMIC_RELAXED, __HIP_MEMORY_SCOPE_AGENT);
        }
        if ((unsigned)(a >> 32) == want && (unsigned)(b >> 32) == want) break;
    }
    return make_float2(__uint_as_float((unsigned)a), __uint_as_float((unsigned)b));
}

// Dual publish: both stores fire-and-forget (tag travels with value in 8B).
__device__ __forceinline__ void publish(volatile unsigned long long* Fd,
                                        unsigned long long* Sd,
                                        unsigned long long pk)
{
    *Fd = pk;   // write-through L1 -> local L2 (fast, same-XCD visible)
    __hip_atomic_store(Sd, pk, __ATOMIC_RELAXED, __HIP_MEMORY_SCOPE_AGENT);
}

__global__ __launch_bounds__(NTHR, 2)
void rnn_fused(const int* __restrict__ xs, const float* __restrict__ h0,
               const float* __restrict__ U, const float* __restrict__ W,
               const float* __restrict__ V, const float* __restrict__ bh,
               const float* __restrict__ by, float* __restrict__ out,
               int* __restrict__ ctrl,
               unsigned long long* __restrict__ htagF,
               unsigned long long* __restrict__ htagS)
{
    const int tid = threadIdx.x;

    // ---- election: find 32 co-XCD blocks (resolves by pigeonhole) ----
    __shared__ int s_slice;
    if (tid == 0) {
        int xcd;
        asm volatile("s_getreg_b32 %0, hwreg(HW_REG_XCC_ID)" : "=s"(xcd));
        xcd &= 7;
        const int r = __hip_atomic_fetch_add(&ctrl[1 + xcd], 1,
                                             __ATOMIC_RELAXED, __HIP_MEMORY_SCOPE_AGENT);
        if (r == NWORK - 1) {
            int expected = 0;
            __hip_atomic_compare_exchange_strong(&ctrl[0], &expected, xcd + 1,
                __ATOMIC_RELAXED, __ATOMIC_RELAXED, __HIP_MEMORY_SCOPE_AGENT);
        }
        int ch;
        do {
            ch = __hip_atomic_load(&ctrl[0], __ATOMIC_RELAXED, __HIP_MEMORY_SCOPE_AGENT);
        } while (ch == 0);
        s_slice = (ch - 1 == xcd && r < NWORK) ? r : -1;
    }
    __syncthreads();
    const int b = s_slice;
    if (b < 0) return;                  // not a worker

    const int w = tid >> 6;             // wave 0..7
    const int l = tid & 63;             // lane

    __shared__ float hl[2][H_DIM];      // double-buffered swizzled h

    // ---- W fragment: rows wr0..wr0+3, k in [16l, 16l+16) ----
    const int wr0 = b * 32 + w * 4;
    float4 wreg[4][4];
#pragma unroll
    for (int j = 0; j < 4; ++j)
#pragma unroll
        for (int q = 0; q < 4; ++q)
            wreg[j][q] = *(const float4*)(W + (size_t)(wr0 + j) * H_DIM + 16 * l + 4 * q);
    const float bh_r = bh[wr0 + (l & 3)];
    const int   urow = wr0 + (l & 3);

    // ---- V fragment: rows vr0, vr0+1, same k-chunk ----
    const int vr0 = b * 16 + w * 2;
    float4 vreg[2][4];
#pragma unroll
    for (int m = 0; m < 2; ++m)
#pragma unroll
        for (int q = 0; q < 4; ++q)
            vreg[m][q] = *(const float4*)(V + (size_t)(vr0 + m) * H_DIM + 16 * l + 4 * q);
    const float by_r = by[vr0 + (l & 1)];

    // ---- LDS addresses (dwords), quad-XOR swizzle ----
    int rdw[4];
#pragma unroll
    for (int q = 0; q < 4; ++q)
        rdw[q] = 16 * l + 4 * (q ^ ((l >> 1) & 3));
    const int c   = tid >> 3;
    const int qw  = (tid >> 1) & 3;
    const int wdw = 16 * c + 4 * (qw ^ ((c >> 1) & 3)) + 2 * (tid & 1);

    const bool o1 = (l & 1) != 0, o2 = (l & 2) != 0;

    for (int t = 0; t < T_STEPS; ++t) {
        const int sb = (~t) & 1;
        float* hb = hl[sb];

        const int   xt = xs[t];
        const float uv = U[(size_t)urow * D_DIM + xt];   // hidden under poll

        // ---- acquire h^{(t)}: poll own 2 tagged words, dual channel ----
        float2 hpair;
        if (t == 0) {
            hpair = *(const float2*)(h0 + 2 * tid);
        } else {
            const size_t off = (size_t)((t - 1) & 1) * H_DIM + 2 * tid;
            hpair = acquire_pair(htagF + off, htagS + off, (unsigned)(t - 1));
        }
        *(float2*)&hb[wdw] = hpair;
        __syncthreads();

        // ---- critical path: 16 h floats, 64 FMAs, fused select+reduce ----
        float4 h4[4];
#pragma unroll
        for (int q = 0; q < 4; ++q) h4[q] = *(const float4*)&hb[rdw[q]];

        float s[4];
#pragma unroll
        for (int j = 0; j < 4; ++j) {
            float4 a = make_float4(0.f, 0.f, 0.f, 0.f);
#pragma unroll
            for (int q = 0; q < 4; ++q) {
                a.x += wreg[j][q].x * h4[q].x;
                a.y += wreg[j][q].y * h4[q].y;
                a.z += wreg[j][q].z * h4[q].z;
                a.w += wreg[j][q].w * h4[q].w;
            }
            s[j] = hsum4(a);
        }
        float A  = o1 ? s[1] : s[0], Ax = o1 ? s[0] : s[1];
        float B  = o1 ? s[3] : s[2], Bx = o1 ? s[2] : s[3];
        A += __shfl_xor(Ax, 1);
        B += __shfl_xor(Bx, 1);
        float Cv = o2 ? B : A, Cx = o2 ? A : B;
        Cv += __shfl_xor(Cx, 2);
        Cv += __shfl_xor(Cv, 4);
        Cv += __shfl_xor(Cv, 8);
        Cv += __shfl_xor(Cv, 16);
        Cv += __shfl_xor(Cv, 32);

        const float hv = fast_tanh(Cv + bh_r + uv);
        if (l < 4) {
            const unsigned long long pk =
                ((unsigned long long)(unsigned)t << 32) | (unsigned long long)__float_as_uint(hv);
            const size_t doff = (size_t)(t & 1) * H_DIM + wr0 + l;
            publish(htagF + doff, htagS + doff, pk);
        }

        // ---- hidden window: logits[t-1] from h4 registers ----
        if (t > 0) {
            float sv[2];
#pragma unroll
            for (int m = 0; m < 2; ++m) {
                float4 a = make_float4(0.f, 0.f, 0.f, 0.f);
#pragma unroll
                for (int q = 0; q < 4; ++q) {
                    a.x += vreg[m][q].x * h4[q].x;
                    a.y += vreg[m][q].y * h4[q].y;
                    a.z += vreg[m][q].z * h4[q].z;
                    a.w += vreg[m][q].w * h4[q].w;
                }
                sv[m] = hsum4(a);
            }
            float P  = o1 ? sv[1] : sv[0], Px = o1 ? sv[0] : sv[1];
            P += __shfl_xor(Px, 1);
            P += __shfl_xor(P, 2);
            P += __shfl_xor(P, 4);
            P += __shfl_xor(P, 8);
            P += __shfl_xor(P, 16);
            P += __shfl_xor(P, 32);
            if (l < 2) out[(size_t)(t - 1) * O_DIM + vr0 + l] = P + by_r;
        }
    }

    // ---- epilogue: h_T (tag T-1, parity 1) -> out tail + logits[T-1] ----
    {
        const size_t off = (size_t)((T_STEPS - 1) & 1) * H_DIM + 2 * tid;
        float2 hpair = acquire_pair(htagF + off, htagS + off, (unsigned)(T_STEPS - 1));
        if (b == 0)
            *(float2*)&out[(size_t)T_STEPS * O_DIM + 2 * tid] = hpair;

        float* hb = hl[1];
        *(float2*)&hb[wdw] = hpair;
        __syncthreads();
        float4 h4[4];
#pragma unroll
        for (int q = 0; q < 4; ++q) h4[q] = *(const float4*)&hb[rdw[q]];
        float sv[2];
#pragma unroll
        for (int m = 0; m < 2; ++m) {
            float4 a = make_float4(0.f, 0.f, 0.f, 0.f);
#pragma unroll
            for (int q = 0; q < 4; ++q) {
                a.x += vreg[m][q].x * h4[q].x;
                a.y += vreg[m][q].y * h4[q].y;
                a.z += vreg[m][q].z * h4[q].z;
                a.w += vreg[m][q].w * h4[q].w;
            }
            sv[m] = hsum4(a);
        }
        float P  = o1 ? sv[1] : sv[0], Px = o1 ? sv[0] : sv[1];
        P += __shfl_xor(Px, 1);
        P += __shfl_xor(P, 2);
        P += __shfl_xor(P, 4);
        P += __shfl_xor(P, 8);
        P += __shfl_xor(P, 16);
        P += __shfl_xor(P, 32);
        if (l < 2) out[(size_t)(T_STEPS - 1) * O_DIM + vr0 + l] = P + by_r;
    }
}

extern "C" void kernel_launch(void* const* d_in, const int* in_sizes, int n_in,
                              void* d_out, int out_size, void* d_ws, size_t ws_size,
                              hipStream_t stream) {
    const int*   xs = (const int*)d_in[0];
    const float* h0 = (const float*)d_in[1];
    const float* U  = (const float*)d_in[2];
    const float* W  = (const float*)d_in[3];
    const float* V  = (const float*)d_in[4];
    const float* bh = (const float*)d_in[5];
    const float* by = (const float*)d_in[6];
    float* out = (float*)d_out;

    // ws: [ctrl 256 B: chosen(+1)@0, cnt[8]@4..36]
    //     [htagF 2*1024 u64][htagS 2*1024 u64]
    int* ctrl = (int*)d_ws;
    unsigned long long* htagF = (unsigned long long*)((char*)d_ws + 256);
    unsigned long long* htagS = htagF + 2 * H_DIM;

    hipMemsetAsync(d_ws, 0, 256, stream);                       // election state
    hipMemsetAsync((char*)d_ws + 256, 0xAA,
                   4 * H_DIM * sizeof(unsigned long long), stream);  // invalid tags

    rnn_fused<<<NGRID, NTHR, 0, stream>>>(xs, h0, U, W, V, bh, by, out,
                                          ctrl, htagF, htagS);
}